// Round 6
// baseline (142.953 us; speedup 1.0000x reference)
//
#include <hip/hip_runtime.h>
#include <hip/hip_bf16.h>

#define B_N 16384
#define D_K 128
#define NBLK 64          // 64 blocks of 256 rows/cols
#define NPAIR 2080       // NBLK*(NBLK+1)/2 upper-triangle pairs

typedef __bf16 bf16x8 __attribute__((ext_vector_type(8)));
typedef float f32x4 __attribute__((ext_vector_type(4)));
typedef float f32x2 __attribute__((ext_vector_type(2)));

#if defined(__has_builtin)
#if __has_builtin(__builtin_amdgcn_exp2f)
#define EXP2F(x) __builtin_amdgcn_exp2f(x)
#else
#define EXP2F(x) exp2f(x)
#endif
#else
#define EXP2F(x) exp2f(x)
#endif

__device__ __forceinline__ void gload_lds16(const void* g, void* l) {
  __builtin_amdgcn_global_load_lds(
      (const __attribute__((address_space(1))) unsigned int*)g,
      (__attribute__((address_space(3))) unsigned int*)l, 16, 0, 0);
}

// ---------------- kernel 1: normalize rows, prescale by sqrt(1/(T*ln2)), build col weights
__global__ __launch_bounds__(256) void prep_kernel(
    const float* __restrict__ E, const int* __restrict__ labels,
    const int* __restrict__ mask, __hip_bfloat16* __restrict__ Ebf,
    float2* __restrict__ W)
{
  int tid = threadIdx.x;
  int gtid = blockIdx.x * 256 + tid;
  if (gtid < B_N) {
    int lb = labels[gtid];
    float wm = (mask[gtid] != 0) ? 1.0f : 0.0f;
    W[gtid] = make_float2((lb == 0) ? wm : 0.0f, wm);
  }
  int lane = tid & 63;
  int wid = gtid >> 6;
  const float2* E2 = (const float2*)E;
  __hip_bfloat162* O2 = (__hip_bfloat162*)Ebf;
  for (int row = wid; row < B_N; row += 4096) {
    float2 v = E2[row * 64 + lane];
    float ss = v.x * v.x + v.y * v.y;
    #pragma unroll
    for (int m = 1; m < 64; m <<= 1) ss += __shfl_xor(ss, m);
    // sqrt(14.426950408889634) = sqrt(1/(0.1*ln2)); folded into both operands
    float sc = 3.7982826f / fmaxf(sqrtf(ss), 1e-12f);
    __hip_bfloat162 h;
    h.x = __float2bfloat16(v.x * sc);
    h.y = __float2bfloat16(v.y * sc);
    O2[row * 64 + lane] = h;
  }
}

// ---------------- kernel 2 (symmetric pair version)
// Pair (I,J), I<=J: compute exp-tile once. I-side: rows of I get w(col)-weighted row
// sums (lane reduction). J-side: rows of J get w(row)-weighted COLUMN sums (lg-group
// reduction). Evidence R2/R4/R5: wall tracks per-element work -> halve the elements.
template<bool DIAG, bool JSIDE>
__device__ __forceinline__ void tile_compute_pair(
    const char* lds, const char* ldsW, const bf16x8 a[4][4],
    const f32x2 wRow[4][4], int C0loc, int colBase, int lane, int WR0,
    f32x2 accI[4][4], f32x2 cs[4])
{
  const int l15 = lane & 15, lg = lane >> 4, l7 = lane & 7;
  #pragma unroll
  for (int nf = 0; nf < 4; ++nf) {   // 4 x 16 = 64 cols
    int col = nf * 16 + l15;
    int colg = colBase + C0loc + col;
    f32x2 wv = *(const f32x2*)(ldsW + ((C0loc + col) << 3));  // w(col), broadcast
    bf16x8 b[4];
    #pragma unroll
    for (int kk = 0; kk < 4; ++kk) {
      int addr = col * 256 + (((kk * 4 + lg) ^ l7) << 4);  // XOR-swizzled chunk
      b[kk] = *(const bf16x8*)(lds + addr);
    }
    f32x4 c[4];
    __builtin_amdgcn_s_setprio(1);
    #pragma unroll
    for (int mf = 0; mf < 4; ++mf) {
      f32x4 t = {0.f, 0.f, 0.f, 0.f};
      #pragma unroll
      for (int kk = 0; kk < 4; ++kk)
        t = __builtin_amdgcn_mfma_f32_16x16x32_bf16(a[mf][kk], b[kk], t, 0, 0, 0);
      c[mf] = t;
    }
    __builtin_amdgcn_s_setprio(0);
    #pragma unroll
    for (int mf = 0; mf < 4; ++mf) {
      #pragma unroll
      for (int r = 0; r < 4; ++r) {
        float p = EXP2F(c[mf][r]);     // exp(sim/T), scale folded into operands
        if (DIAG) {
          int rowg = WR0 + mf * 16 + lg * 4 + r;   // verified C/D layout
          p = (rowg == colg) ? 0.0f : p;
        }
        accI[mf][r] += wv * p;                      // I-side: w(col)-weighted row sum
        if (JSIDE) cs[nf] += wRow[mf][r] * p;       // J-side: w(row)-weighted col sum
      }
    }
  }
}

__global__ __launch_bounds__(256, 2) void gemm_pair(
    const __hip_bfloat16* __restrict__ Ebf, const float2* __restrict__ W,
    float2* __restrict__ SW)
{
  __shared__ alignas(16) char smem[65536];
  char* ldsW = smem;                       // 2 KB: w(col) for J's 256 cols
  float2* cbuf = (float2*)(smem + 2048);   // 8 KB: cross-wave colsum reduce
  char* ring = smem + 16384;               // 3 x 16 KB tile ring

  const int tid = threadIdx.x;
  const int lane = tid & 63;
  const int w = tid >> 6;
  const int l15 = lane & 15, lg = lane >> 4;

  // decode upper-triangle pair (I <= J); consecutive bids share I (L2 locality)
  int I = 0, k = blockIdx.x;
  while (k >= NBLK - I) { k -= NBLK - I; ++I; }
  const int J = I + k;

  const int R0 = I * 256;
  const int WR0 = R0 + w * 64;   // this wave's 64 rows
  const int colBase = J * 256;

  // --- prologue VGPR loads (must precede stages for the vmcnt discipline) ---
  bf16x8 a[4][4];                // A fragments: 64 rows x K=128
  #pragma unroll
  for (int mf = 0; mf < 4; ++mf)
    #pragma unroll
    for (int kk = 0; kk < 4; ++kk) {
      int row = WR0 + mf * 16 + l15;
      a[mf][kk] = *(const bf16x8*)(Ebf + (size_t)row * D_K + kk * 32 + lg * 8);
    }
  f32x2 wRow[4][4];              // w(row) for this lane's 16 accumulator rows
  #pragma unroll
  for (int mf = 0; mf < 4; ++mf)
    #pragma unroll
    for (int r = 0; r < 4; ++r)
      wRow[mf][r] = *(const f32x2*)&W[WR0 + mf * 16 + lg * 4 + r];

  // stage w(col) slice: 2KB = 128 x 16B chunks, threads 0..127
  if (tid < 128)
    gload_lds16((const char*)(W + colBase) + tid * 16, ldsW + tid * 16);

  // staging offsets: linear LDS dest, swizzle on the GLOBAL source (m173 pattern)
  int goff[4], loff[4];
  #pragma unroll
  for (int i = 0; i < 4; ++i) {
    int q = i * 4 + w;
    int col = q * 4 + lg;
    int c = l15 ^ (col & 7);
    goff[i] = col * D_K + c * 8;
    loff[i] = q * 1024;
  }

  // stage tiles 0,1 (ring depth 2 in flight)
  {
    const __hip_bfloat16* s0 = Ebf + (size_t)colBase * D_K;
    #pragma unroll
    for (int i = 0; i < 4; ++i) gload_lds16(s0 + goff[i], ring + loff[i]);
    const __hip_bfloat16* s1 = Ebf + (size_t)(colBase + 64) * D_K;
    #pragma unroll
    for (int i = 0; i < 4; ++i) gload_lds16(s1 + goff[i], ring + 16384 + loff[i]);
  }
  __builtin_amdgcn_sched_barrier(0);   // pin all prologue loads above the loop

  f32x2 accI[4][4] = {};
  f32x2 cs[4][4] = {};   // [subtile t][nf] column sums (static indices via unroll)
  const bool diagPair = (I == J);

  #pragma unroll
  for (int t = 0; t < 4; ++t) {
    // counted wait: newest 4 outstanding = tile t+1's stage; everything older landed
    if (t < 3) asm volatile("s_waitcnt vmcnt(4)" ::: "memory");
    else       asm volatile("s_waitcnt vmcnt(0)" ::: "memory");
    __builtin_amdgcn_s_barrier();
    asm volatile("" ::: "memory");
    if (t + 2 < 4) {   // stage t+2 into buf (t+2)%3 (== buf (t-1)%3: its compute is done)
      const __hip_bfloat16* src = Ebf + (size_t)(colBase + ((t + 2) << 6)) * D_K;
      char* dst = ring + ((t + 2) % 3) * 16384;
      #pragma unroll
      for (int i = 0; i < 4; ++i) gload_lds16(src + goff[i], dst + loff[i]);
    }
    const char* lds = ring + (t % 3) * 16384;
    if (diagPair)
      tile_compute_pair<true,  false>(lds, ldsW, a, wRow, t << 6, colBase, lane, WR0, accI, cs[t]);
    else
      tile_compute_pair<false, true >(lds, ldsW, a, wRow, t << 6, colBase, lane, WR0, accI, cs[t]);
  }

  // ---- I-side write: slot J, rows of I (16-lane reduction as before)
  #pragma unroll
  for (int mf = 0; mf < 4; ++mf) {
    #pragma unroll
    for (int r = 0; r < 4; ++r) {
      float s0 = accI[mf][r].x, tt = accI[mf][r].y;
      #pragma unroll
      for (int m = 1; m < 16; m <<= 1) {
        s0 += __shfl_xor(s0, m);
        tt += __shfl_xor(tt, m);
      }
      if (l15 == 0) {
        int rowg = WR0 + mf * 16 + lg * 4 + r;
        SW[(size_t)J * B_N + rowg] = make_float2(s0, tt);
      }
    }
  }

  // ---- J-side write: slot I, rows of J (column sums; off-diag pairs only)
  if (!diagPair) {
    #pragma unroll
    for (int t = 0; t < 4; ++t) {
      #pragma unroll
      for (int nf = 0; nf < 4; ++nf) {
        float x = cs[t][nf].x, y = cs[t][nf].y;
        x += __shfl_xor(x, 16); x += __shfl_xor(x, 32);   // reduce over lg groups
        y += __shfl_xor(y, 16); y += __shfl_xor(y, 32);
        if (lg == 0) cbuf[w * 256 + t * 64 + nf * 16 + l15] = make_float2(x, y);
      }
    }
    __syncthreads();
    {
      float2 v0 = cbuf[tid], v1 = cbuf[256 + tid], v2 = cbuf[512 + tid], v3 = cbuf[768 + tid];
      SW[(size_t)I * B_N + colBase + tid] =
          make_float2(v0.x + v1.x + v2.x + v3.x, v0.y + v1.y + v2.y + v3.y);
    }
  }
}

// ---------------- fallback kernel 2 (R5 split version, used only if workspace is tight)
template<bool DIAG>
__device__ __forceinline__ void tile_compute(
    const char* lds, const char* ldsW, const bf16x8 a[4][4],
    int C0loc, int colBase, int lane, int WR0,
    f32x2 acc[4][4])
{
  const int l15 = lane & 15, lg = lane >> 4, l7 = lane & 7;
  #pragma unroll
  for (int nf = 0; nf < 4; ++nf) {
    int col = nf * 16 + l15;
    int colg = colBase + C0loc + col;
    f32x2 wv = *(const f32x2*)(ldsW + ((C0loc + col) << 3));
    bf16x8 b[4];
    #pragma unroll
    for (int kk = 0; kk < 4; ++kk) {
      int addr = col * 256 + (((kk * 4 + lg) ^ l7) << 4);
      b[kk] = *(const bf16x8*)(lds + addr);
    }
    f32x4 c[4];
    __builtin_amdgcn_s_setprio(1);
    #pragma unroll
    for (int mf = 0; mf < 4; ++mf) {
      f32x4 t = {0.f, 0.f, 0.f, 0.f};
      #pragma unroll
      for (int kk = 0; kk < 4; ++kk)
        t = __builtin_amdgcn_mfma_f32_16x16x32_bf16(a[mf][kk], b[kk], t, 0, 0, 0);
      c[mf] = t;
    }
    __builtin_amdgcn_s_setprio(0);
    #pragma unroll
    for (int mf = 0; mf < 4; ++mf) {
      #pragma unroll
      for (int r = 0; r < 4; ++r) {
        float p = EXP2F(c[mf][r]);
        if (DIAG) {
          int rowg = WR0 + mf * 16 + lg * 4 + r;
          p = (rowg == colg) ? 0.0f : p;
        }
        acc[mf][r] += wv * p;
      }
    }
  }
}

__global__ __launch_bounds__(256, 2) void gemm_kernel(
    const __hip_bfloat16* __restrict__ Ebf, const float2* __restrict__ W,
    float2* __restrict__ SW, int colsPerSplit)
{
  __shared__ alignas(16) char smem[65536];
  char* ldsW  = smem;
  char* tiles = smem + 16384;

  const int tid = threadIdx.x;
  const int lane = tid & 63;
  const int w = tid >> 6;
  const int R0 = blockIdx.x * 256;
  const int WR0 = R0 + w * 64;
  const int l15 = lane & 15, lg = lane >> 4;

  bf16x8 a[4][4];
  #pragma unroll
  for (int mf = 0; mf < 4; ++mf)
    #pragma unroll
    for (int kk = 0; kk < 4; ++kk) {
      int row = WR0 + mf * 16 + l15;
      a[mf][kk] = *(const bf16x8*)(Ebf + (size_t)row * D_K + kk * 32 + lg * 8);
    }

  int goff[4], loff[4];
  #pragma unroll
  for (int i = 0; i < 4; ++i) {
    int q = i * 4 + w;
    int col = q * 4 + lg;
    int c = l15 ^ (col & 7);
    goff[i] = col * D_K + c * 8;
    loff[i] = q * 1024;
  }

  f32x2 acc[4][4] = {};
  const int colBase = blockIdx.y * colsPerSplit;
  const int nt = colsPerSplit >> 6;

  {
    const char* wsrc = (const char*)(W + colBase);
    int nW = colsPerSplit >> 9;
    for (int i = 0; i < nW; ++i)
      gload_lds16(wsrc + (((i * 4 + w) * 64 + lane) << 4), ldsW + ((i * 4 + w) << 10));
  }
  {
    const __hip_bfloat16* src0 = Ebf + (size_t)colBase * D_K;
    #pragma unroll
    for (int i = 0; i < 4; ++i) gload_lds16(src0 + goff[i], tiles + loff[i]);
    if (nt > 1) {
      const __hip_bfloat16* src1 = Ebf + (size_t)(colBase + 64) * D_K;
      #pragma unroll
      for (int i = 0; i < 4; ++i) gload_lds16(src1 + goff[i], tiles + 16384 + loff[i]);
    }
  }

  int bufOff = 0;
  for (int t = 0; t < nt; ++t) {
    if (t + 1 < nt) asm volatile("s_waitcnt vmcnt(4)" ::: "memory");
    else            asm volatile("s_waitcnt vmcnt(0)" ::: "memory");
    __builtin_amdgcn_s_barrier();
    asm volatile("" ::: "memory");
    if (t + 2 < nt) {
      int nb = bufOff + 32768; if (nb >= 49152) nb -= 49152;
      const __hip_bfloat16* src = Ebf + (size_t)(colBase + ((t + 2) << 6)) * D_K;
      #pragma unroll
      for (int i = 0; i < 4; ++i) gload_lds16(src + goff[i], tiles + nb + loff[i]);
    }
    const int C0loc = t << 6;
    const int Cg = colBase + C0loc;
    const bool diag = (Cg < R0 + 256) && (Cg + 64 > R0);
    if (diag) tile_compute<true >(tiles + bufOff, ldsW, a, C0loc, colBase, lane, WR0, acc);
    else      tile_compute<false>(tiles + bufOff, ldsW, a, C0loc, colBase, lane, WR0, acc);
    bufOff += 16384; if (bufOff == 49152) bufOff = 0;
  }

  #pragma unroll
  for (int mf = 0; mf < 4; ++mf) {
    #pragma unroll
    for (int r = 0; r < 4; ++r) {
      float s0 = acc[mf][r].x, tt = acc[mf][r].y;
      #pragma unroll
      for (int m = 1; m < 16; m <<= 1) {
        s0 += __shfl_xor(s0, m);
        tt += __shfl_xor(tt, m);
      }
      if (l15 == 0) {
        int rowg = WR0 + mf * 16 + lg * 4 + r;
        SW[(size_t)blockIdx.y * B_N + rowg] = make_float2(s0, tt);
      }
    }
  }
}

// ---------------- kernel 3a: per-row loss, deterministic partials
__global__ __launch_bounds__(256) void loss_part(
    const int* __restrict__ labels, const int* __restrict__ mask,
    const float2* __restrict__ SW, int NS, float2* __restrict__ partial)
{
  __shared__ int sc0[4], sc1[4];
  __shared__ float st[4], sn[4];
  int tid = threadIdx.x, lane = tid & 63, wv = tid >> 6;

  int c0 = 0, c1 = 0;
  for (int i = tid; i < B_N; i += 256) {
    if (mask[i] != 0) { if (labels[i] == 0) c0++; else c1++; }
  }
  #pragma unroll
  for (int m = 1; m < 64; m <<= 1) { c0 += __shfl_xor(c0, m); c1 += __shfl_xor(c1, m); }
  if (lane == 0) { sc0[wv] = c0; sc1[wv] = c1; }
  __syncthreads();
  int cnt0 = sc0[0] + sc0[1] + sc0[2] + sc0[3];
  int cnt1 = sc1[0] + sc1[1] + sc1[2] + sc1[3];

  int r = blockIdx.x * 256 + tid;
  float s0 = 0.f, tt = 0.f;
  for (int s = 0; s < NS; ++s) {
    float2 v = SW[(size_t)s * B_N + r];
    s0 += v.x; tt += v.y;
  }
  int lb = labels[r];
  float pos = (lb == 0) ? s0 : (tt - s0);
  int cnt = (lb == 0) ? cnt0 : cnt1;
  float tot = 0.f, nv = 0.f;
  if (mask[r] != 0 && cnt > 1) {
    tot = logf(tt + 1e-8f) - logf(pos);
    nv = 1.f;
  }
  #pragma unroll
  for (int m = 1; m < 64; m <<= 1) { tot += __shfl_xor(tot, m); nv += __shfl_xor(nv, m); }
  if (lane == 0) { st[wv] = tot; sn[wv] = nv; }
  __syncthreads();
  if (tid == 0) {
    partial[blockIdx.x] = make_float2(st[0] + st[1] + st[2] + st[3],
                                      sn[0] + sn[1] + sn[2] + sn[3]);
  }
}

// ---------------- kernel 3b: final deterministic reduce (one wave)
__global__ __launch_bounds__(64) void loss_final(
    const float2* __restrict__ partial, int nb, float* __restrict__ out)
{
  int lane = threadIdx.x;
  float t = 0.f, n = 0.f;
  for (int i = lane; i < nb; i += 64) {
    float2 v = partial[i];
    t += v.x; n += v.y;
  }
  #pragma unroll
  for (int m = 1; m < 64; m <<= 1) { t += __shfl_xor(t, m); n += __shfl_xor(n, m); }
  if (lane == 0) out[0] = (n > 0.f) ? t / fmaxf(n, 1.f) : 0.f;
}

extern "C" void kernel_launch(void* const* d_in, const int* in_sizes, int n_in,
                              void* d_out, int out_size, void* d_ws, size_t ws_size,
                              hipStream_t stream)
{
  const float* E = (const float*)d_in[0];
  const int* labels = (const int*)d_in[1];
  const int* mask = (const int*)d_in[2];

  char* ws = (char*)d_ws;
  __hip_bfloat16* Ebf = (__hip_bfloat16*)ws;                       // 4 MB
  float2* W = (float2*)(ws + (size_t)B_N * D_K * 2);               // 128 KB
  float2* SW = (float2*)(ws + (size_t)B_N * D_K * 2 + (size_t)B_N * 8);
  size_t base = (size_t)B_N * D_K * 2 + (size_t)B_N * 8;

  prep_kernel<<<1024, 256, 0, stream>>>(E, labels, mask, Ebf, W);

  size_t needSym = base + (size_t)NBLK * B_N * 8 + 1024;
  if (ws_size >= needSym) {
    // symmetric pair path: each of the 2080 block-pairs computed once
    float2* partial = (float2*)(ws + base + (size_t)NBLK * B_N * 8);
    gemm_pair<<<NPAIR, 256, 0, stream>>>(Ebf, W, SW);
    loss_part<<<B_N / 256, 256, 0, stream>>>(labels, mask, SW, NBLK, partial);
    loss_final<<<1, 64, 0, stream>>>(partial, B_N / 256, (float*)d_out);
  } else {
    // fallback: non-symmetric col-split path (R5)
    int NS = 16;
    while (NS > 8 && base + (size_t)NS * B_N * 8 + 1024 > ws_size) NS >>= 1;
    int cps = B_N / NS;
    float2* partial = (float2*)(ws + base + (size_t)NS * B_N * 8);
    dim3 g2(B_N / 256, NS);
    gemm_kernel<<<g2, 256, 0, stream>>>(Ebf, W, SW, cps);
    loss_part<<<B_N / 256, 256, 0, stream>>>(labels, mask, SW, NS, partial);
    loss_final<<<1, 64, 0, stream>>>(partial, B_N / 256, (float*)d_out);
  }
}